// Round 2
// baseline (3451.378 us; speedup 1.0000x reference)
//
#include <hip/hip_runtime.h>

#define TT  464
#define HH  256
#define BB  64

using bf16x8 = __attribute__((ext_vector_type(8))) short;   // 8 bf16 (4 VGPRs)
using f32x4  = __attribute__((ext_vector_type(4))) float;   // MFMA accumulator

__device__ __forceinline__ unsigned short f2bf(float x) {
  union { float f; unsigned u; } v; v.f = x;
  unsigned r = v.u + 0x7fffu + ((v.u >> 16) & 1u);   // RNE
  return (unsigned short)(r >> 16);
}

// 4-flag barrier wait (fan-in 4): lanes poll the group's 4 flags, no sleep.
__device__ __forceinline__ void wait_flags(int* flags, int base, int target) {
  const int ln = threadIdx.x & 63;
  int* p = &flags[base + (ln & 3)];
  for (;;) {
    int f = __hip_atomic_load(p, __ATOMIC_RELAXED, __HIP_MEMORY_SCOPE_AGENT);
    if (__all(f >= target)) break;
  }
  asm volatile("" ::: "memory");   // keep h loads below the poll
}

// Persistent LSTM, 8 WGs = 2 batch-groups x 4 unit-groups.
// WG owns 32 batch rows x 64 hidden units; full [W;U] slice lives in REGISTERS
// (bf16x8 wW[4][8] + wU[4][8] = 256 VGPRs/lane), so the per-step rendezvous
// fan-in is 4 WGs instead of 32. Gate epilogue is lane-local (MFMA C layout:
// col=lane&15 -> unit, row=q*4+reg -> batch row): no z_lds exchange, one
// barrier per step. x staged via double-buffered LDS in the shadow region.
__global__ __launch_bounds__(256, 1) void lstm_kernel(
    const float* __restrict__ x,      // [64][464][256]
    const float* __restrict__ h0,     // [64][256]
    const float* __restrict__ c0,     // [64][256]
    const float* __restrict__ W,      // [256][1024]
    const float* __restrict__ U,      // [256][1024]
    const float* __restrict__ bias,   // [1024]
    unsigned int* __restrict__ h_bufs,   // [2][64][128] u32 (= [2][64][256] bf16)
    unsigned short* __restrict__ seq,    // [64][464][256] bf16
    float* __restrict__ out,             // [0:16384) core, [16384) hT, [32768) cT
    int* __restrict__ flags)             // flags[bgi*16 + ugi]
{
  const int tid = threadIdx.x;
  const int wg  = blockIdx.x;       // 0..7
  const int bgi = wg >> 2;          // 0..1  batch group (32 rows)
  const int ugi = wg & 3;           // 0..3  unit group (64 hidden units)
  const int wv  = tid >> 6;         // wave 0..3 -> 16-unit slice
  const int ln  = tid & 63;
  const int l15 = ln & 15;
  const int q   = ln >> 4;

  // LDS: weight-staging buffer (prologue only) aliased with x double-buffer.
  __shared__ __align__(16) char smem[33792];   // max(32*520*2, 2*32*264*2)
  unsigned short (*Bst)[520]     = (unsigned short(*)[520])smem;      // [32][520]
  unsigned short (*xl)[32][264]  = (unsigned short(*)[32][264])smem;  // [2][32][264]

  // ---------------- Prologue: weights -> registers ----------------
  bf16x8 wW[4][8], wU[4][8];
  const int ubase = ugi * 64;
#pragma unroll
  for (int g = 0; g < 4; ++g) {
#pragma unroll
    for (int half = 0; half < 2; ++half) {
      __syncthreads();                         // prev chunk's reads done
      const int cbase = g * 256 + ubase + half * 32;
      for (int it = 0; it < 64; ++it) {        // stage [32 cols][512 k] bf16
        int idx = it * 256 + tid;              // 16384 elems = 64 iters x 256 thr
        int k = idx >> 5, n = idx & 31;
        float val = (k < 256) ? W[(size_t)k * 1024 + cbase + n]
                              : U[(size_t)(k - 256) * 1024 + cbase + n];
        Bst[n][k] = f2bf(val);
      }
      __syncthreads();
      if ((wv >> 1) == half) {                 // this wave's 16-col slice
#pragma unroll
        for (int kk = 0; kk < 8; ++kk) {
          wW[g][kk] = *(const bf16x8*)&Bst[(wv & 1) * 16 + l15][kk * 32 + q * 8];
          wU[g][kk] = *(const bf16x8*)&Bst[(wv & 1) * 16 + l15][256 + kk * 32 + q * 8];
        }
      }
    }
  }
  __syncthreads();   // Bst dead; xl may now be written (aliased)

  // ---------------- State: 8 (row, unit) pairs per lane ----------------
  const int u   = ubase + wv * 16 + l15;       // hidden unit (C col = l15)
  const int rb  = bgi * 32;                    // group row base
  const float b_i = bias[u], b_f = bias[256 + u], b_g = bias[512 + u], b_o = bias[768 + u];
  float cst[2][4], hst[2][4];
#pragma unroll
  for (int mt = 0; mt < 2; ++mt)
#pragma unroll
    for (int r = 0; r < 4; ++r) {
      int row = rb + mt * 16 + q * 4 + r;
      cst[mt][r] = c0[row * HH + u];
      hst[mt][r] = h0[row * HH + u];
    }

  // publish h0 into buf 0 (packed u32, relaxed agent atomics -> coherent stores)
#pragma unroll
  for (int mt = 0; mt < 2; ++mt)
#pragma unroll
    for (int r = 0; r < 4; ++r) {
      unsigned short hb16 = f2bf(hst[mt][r]);
      unsigned other = (unsigned)(unsigned short)__shfl_xor((int)hb16, 1);
      if (!(ln & 1)) {
        unsigned hpk = (unsigned)hb16 | (other << 16);
        int row = rb + mt * 16 + q * 4 + r;
        __hip_atomic_store(&h_bufs[row * 128 + (u >> 1)], hpk,
                           __ATOMIC_RELAXED, __HIP_MEMORY_SCOPE_AGENT);
      }
    }

  // ---------------- x staging: thread -> (row r_own, 32 cols) ----------------
  const int r_own = tid >> 3;                  // 0..31 (row within group)
  const int xc0   = (tid & 7) * 32;
  const float* xbase = x + (size_t)(rb + r_own) * TT * HH + xc0;
  float4 xr[8];

  auto stage_x = [&](int buf) {                // xr (fp32) -> bf16 -> xl[buf]
    unsigned px[16];
#pragma unroll
    for (int i = 0; i < 8; ++i) {
      px[2*i]   = (unsigned)f2bf(xr[i].x) | ((unsigned)f2bf(xr[i].y) << 16);
      px[2*i+1] = (unsigned)f2bf(xr[i].z) | ((unsigned)f2bf(xr[i].w) << 16);
    }
#pragma unroll
    for (int s = 0; s < 4; ++s) {
      uint4 v = make_uint4(px[4*s], px[4*s+1], px[4*s+2], px[4*s+3]);
      *(uint4*)&xl[buf][r_own][xc0 + s * 8] = v;
    }
  };

#pragma unroll
  for (int i = 0; i < 8; ++i) xr[i] = ((const float4*)xbase)[i];          // t=0
  stage_x(0);
#pragma unroll
  for (int i = 0; i < 8; ++i) xr[i] = ((const float4*)(xbase + HH))[i];   // t=1

  __builtin_amdgcn_s_waitcnt(0);
  __syncthreads();
  if (tid == 0)
    __hip_atomic_store(&flags[bgi * 16 + ugi], 1, __ATOMIC_RELAXED, __HIP_MEMORY_SCOPE_AGENT);

  // ---------------- 464 recurrent steps ----------------
  for (int t = 0; t < TT; ++t) {
    const int pr  = t & 1;
    const int pwb = pr ^ 1;

    // x @ W (no h dependency; hides under flag propagation)
    f32x4 acc[2][4];
#pragma unroll
    for (int mt = 0; mt < 2; ++mt)
#pragma unroll
      for (int g = 0; g < 4; ++g) acc[mt][g] = (f32x4){0.f, 0.f, 0.f, 0.f};
#pragma unroll
    for (int mt = 0; mt < 2; ++mt)
#pragma unroll
      for (int kk = 0; kk < 8; ++kk) {
        bf16x8 af = *(const bf16x8*)&xl[pr][mt * 16 + l15][kk * 32 + q * 8];
#pragma unroll
        for (int g = 0; g < 4; ++g)
          acc[mt][g] = __builtin_amdgcn_mfma_f32_16x16x32_bf16(af, wW[g][kk], acc[mt][g], 0, 0, 0);
      }

    wait_flags(flags, bgi * 16, t + 1);        // group's 4 WGs published h_t

    // h A-fragments (u64 relaxed agent atomic loads, coherent)
    bf16x8 hf[2][8];
#pragma unroll
    for (int mt = 0; mt < 2; ++mt) {
      const unsigned long long* hb = (const unsigned long long*)h_bufs
          + (size_t)pr * (BB * 64) + (rb + mt * 16 + l15) * 64 + q * 2;
#pragma unroll
      for (int kk = 0; kk < 8; ++kk) {
        union { unsigned long long uu[2]; bf16x8 v; } tmp;
        tmp.uu[0] = __hip_atomic_load(hb + kk * 8,     __ATOMIC_RELAXED, __HIP_MEMORY_SCOPE_AGENT);
        tmp.uu[1] = __hip_atomic_load(hb + kk * 8 + 1, __ATOMIC_RELAXED, __HIP_MEMORY_SCOPE_AGENT);
        hf[mt][kk] = tmp.v;
      }
    }
#pragma unroll
    for (int mt = 0; mt < 2; ++mt)
#pragma unroll
      for (int kk = 0; kk < 8; ++kk)
#pragma unroll
        for (int g = 0; g < 4; ++g)
          acc[mt][g] = __builtin_amdgcn_mfma_f32_16x16x32_bf16(hf[mt][kk], wU[g][kk], acc[mt][g], 0, 0, 0);

    // lane-local gates: acc[mt][gate][reg] is (row = mt*16+q*4+reg, unit = u)
#pragma unroll
    for (int mt = 0; mt < 2; ++mt)
#pragma unroll
      for (int r = 0; r < 4; ++r) {
        float zi = acc[mt][0][r] + b_i;
        float zf = acc[mt][1][r] + b_f;
        float zg = acc[mt][2][r] + b_g;
        float zo = acc[mt][3][r] + b_o;
        float gi = __builtin_amdgcn_rcpf(1.f + __expf(-zi));
        float gf = __builtin_amdgcn_rcpf(1.f + __expf(-zf));
        float go = __builtin_amdgcn_rcpf(1.f + __expf(-zo));
        float c  = gf * cst[mt][r] + gi * fmaxf(zg, 0.f);
        cst[mt][r] = c;
        hst[mt][r] = go * fmaxf(c, 0.f);
      }

    stage_x(pwb);                              // x_{t+1} -> LDS (shadow region)

    // seq + publish h_{t+1} (both drained by the single pre-flag waitcnt)
#pragma unroll
    for (int mt = 0; mt < 2; ++mt)
#pragma unroll
      for (int r = 0; r < 4; ++r) {
        unsigned short hb16 = f2bf(hst[mt][r]);
        unsigned other = (unsigned)(unsigned short)__shfl_xor((int)hb16, 1);
        if (!(ln & 1)) {
          unsigned hpk = (unsigned)hb16 | (other << 16);
          int row = rb + mt * 16 + q * 4 + r;
          *(unsigned*)&seq[((size_t)row * TT + t) * HH + u] = hpk;
          __hip_atomic_store(&h_bufs[pwb * (BB * 128) + row * 128 + (u >> 1)], hpk,
                             __ATOMIC_RELAXED, __HIP_MEMORY_SCOPE_AGENT);
        }
      }

    __builtin_amdgcn_s_waitcnt(0);             // publishes + seq + xl writes drained
    __syncthreads();                           // whole WG drained
    if (tid == 0)
      __hip_atomic_store(&flags[bgi * 16 + ugi], t + 2,
                         __ATOMIC_RELAXED, __HIP_MEMORY_SCOPE_AGENT);

    // prefetch x_{t+2} (drains during next step's wait)
    {
      const int tn = (t + 2 < TT) ? (t + 2) : (TT - 1);
      const float4* p = (const float4*)(xbase + (size_t)tn * HH);
#pragma unroll
      for (int i = 0; i < 8; ++i) xr[i] = p[i];
    }
  }

#pragma unroll
  for (int mt = 0; mt < 2; ++mt)
#pragma unroll
    for (int r = 0; r < 4; ++r) {
      int row = rb + mt * 16 + q * 4 + r;
      out[16384 + row * HH + u] = hst[mt][r];  // hT fp32 (un-rounded state)
      out[32768 + row * HH + u] = cst[mt][r];  // cT
    }
}

// Dense partials: wg kb handles t = kb and kb+232; K=512 per wg.
#define DP_PA 264   // a_lds pitch (shorts)
#define DP_PW 258   // Wf pitch (floats): 258%32=2 -> 2-way on frag reads (free)
__global__ __launch_bounds__(256) void dense_partial(
    const unsigned short* __restrict__ seq,  // [64][464][256] bf16
    const float* __restrict__ Wd,            // [118784][256]
    float* __restrict__ part)                // [232][64][256]
{
  __shared__ __align__(16) char smem[64 * DP_PA * 2];   // 33792 B >= 32*DP_PW*4
  unsigned short* a_lds = (unsigned short*)smem;
  float*          Wf    = (float*)smem;

  const int kb  = blockIdx.x;     // 0..231
  const int tid = threadIdx.x;
  const int wv  = tid >> 6;       // M-tile
  const int ln  = tid & 63;
  const int l15 = ln & 15;
  const int q   = ln >> 4;

  f32x4 acc[16];
#pragma unroll
  for (int i = 0; i < 16; ++i) acc[i] = (f32x4){0.f, 0.f, 0.f, 0.f};

  for (int half = 0; half < 2; ++half) {
    const int t = kb + half * 232;
    __syncthreads();                       // prev chunk's Wf reads done (smem reuse)
#pragma unroll
    for (int it = 0; it < 8; ++it) {       // stage A: seq[0..63][t][:]
      int cidx = it * 256 + tid;
      int row  = cidx >> 5;
      int off  = (cidx & 31) * 8;
      *(bf16x8*)&a_lds[row * DP_PA + off] =
          *(const bf16x8*)(seq + ((size_t)row * TT + t) * HH + off);
    }
    __syncthreads();
    bf16x8 af[8];
#pragma unroll
    for (int kk = 0; kk < 8; ++kk)
      af[kk] = *(const bf16x8*)&a_lds[(wv * 16 + l15) * DP_PA + kk * 32 + q * 8];

    for (int ck = 0; ck < 8; ++ck) {       // K chunks of 32
      __syncthreads();                     // af in regs / prev Wf reads done
#pragma unroll
      for (int it = 0; it < 8; ++it) {     // stage Wf[32][256] fp32, coalesced
        int idx = it * 256 + tid;
        int r   = idx >> 6;
        int c4  = (idx & 63) * 4;
        float4 v = *(const float4*)(Wd + ((size_t)(t * 256 + ck * 32 + r)) * HH + c4);
        *(float2*)&Wf[r * DP_PW + c4]     = make_float2(v.x, v.y);
        *(float2*)&Wf[r * DP_PW + c4 + 2] = make_float2(v.z, v.w);
      }
      __syncthreads();
#pragma unroll
      for (int nt2 = 0; nt2 < 16; ++nt2) {
        const int n = nt2 * 16 + l15;
        bf16x8 bfr;
#pragma unroll
        for (int j = 0; j < 8; ++j)
          bfr[j] = (short)f2bf(Wf[(q * 8 + j) * DP_PW + n]);
        acc[nt2] = __builtin_amdgcn_mfma_f32_16x16x32_bf16(af[ck], bfr, acc[nt2], 0, 0, 0);
      }
    }
  }

  float* pb = part + (size_t)kb * (BB * HH);
#pragma unroll
  for (int nt2 = 0; nt2 < 16; ++nt2)
#pragma unroll
    for (int reg = 0; reg < 4; ++reg)
      pb[(wv * 16 + q * 4 + reg) * HH + nt2 * 16 + l15] = acc[nt2][reg];
}

__global__ __launch_bounds__(256) void dense_reduce(
    const float* __restrict__ part,   // [232][16384]
    const float* __restrict__ bd,     // [256]
    float* __restrict__ out)          // d_out[0:16384)
{
  const int o = blockIdx.x * 256 + threadIdx.x;
  float s0 = 0.f, s1 = 0.f, s2 = 0.f, s3 = 0.f;
  for (int kb = 0; kb < 232; kb += 4) {
    s0 += part[(size_t)(kb    ) * 16384 + o];
    s1 += part[(size_t)(kb + 1) * 16384 + o];
    s2 += part[(size_t)(kb + 2) * 16384 + o];
    s3 += part[(size_t)(kb + 3) * 16384 + o];
  }
  float s = (s0 + s1) + (s2 + s3) + bd[o & 255];
  out[o] = fmaxf(s, 0.f);
}

extern "C" void kernel_launch(void* const* d_in, const int* in_sizes, int n_in,
                              void* d_out, int out_size, void* d_ws, size_t ws_size,
                              hipStream_t stream) {
  const float* x  = (const float*)d_in[0];
  const float* h0 = (const float*)d_in[1];
  const float* c0 = (const float*)d_in[2];
  const float* W  = (const float*)d_in[3];
  const float* U  = (const float*)d_in[4];
  const float* bv = (const float*)d_in[5];
  const float* Wd = (const float*)d_in[6];
  const float* bd = (const float*)d_in[7];
  float* out = (float*)d_out;

  // d_ws layout:
  //   [0,256)        flags (indices bgi*16+ugi; memset to 0 here)
  //   [256, +64KiB)  h_bufs  [2][64][128] u32
  //   next 15.2 MB   seq     [64][464][256] bf16
  //   next 15.2 MB   part    [232][64][256] fp32
  char* w = (char*)d_ws;
  int* flags = (int*)w;
  unsigned int*   h_bufs = (unsigned int*)(w + 256);
  unsigned short* seq    = (unsigned short*)(w + 256 + 2 * BB * HH * 2);
  float*          part   = (float*)(w + 256 + 2 * BB * HH * 2 + (size_t)BB * TT * HH * 2);

  hipMemsetAsync(d_ws, 0, 256, stream);   // reset flags every launch
  lstm_kernel<<<8, 256, 0, stream>>>(x, h0, c0, W, U, bv, h_bufs, seq, out, flags);
  dense_partial<<<232, 256, 0, stream>>>(seq, Wd, part);
  dense_reduce<<<64, 256, 0, stream>>>(part, bd, out);
}

// Round 3
// 3325.372 us; speedup vs baseline: 1.0379x; 1.0379x over previous
//
#include <hip/hip_runtime.h>

#define TT  464
#define HH  256
#define BB  64

using bf16x8 = __attribute__((ext_vector_type(8))) short;   // 8 bf16 (4 VGPRs)
using f32x4  = __attribute__((ext_vector_type(4))) float;   // MFMA accumulator

__device__ __forceinline__ unsigned short f2bf(float x) {
  union { float f; unsigned u; } v; v.f = x;
  unsigned r = v.u + 0x7fffu + ((v.u >> 16) & 1u);   // RNE
  return (unsigned short)(r >> 16);
}

// 8-flag barrier wait (fan-in 8): lanes poll the group's 8 flags, no sleep.
__device__ __forceinline__ void wait_flags(int* flags, int base, int target) {
  const int ln = threadIdx.x & 63;
  int* p = &flags[base + (ln & 7)];
  for (;;) {
    int f = __hip_atomic_load(p, __ATOMIC_RELAXED, __HIP_MEMORY_SCOPE_AGENT);
    if (__all(f >= target)) break;
  }
  asm volatile("" ::: "memory");   // keep h loads below the poll
}

// Persistent LSTM, 16 WGs = 2 batch-groups x 8 unit-groups.
// WG owns 32 batch rows x 32 hidden units; [W;U] slice in registers
// (wW[2][8]+wU[2][8] = 128 VGPRs/lane). Wave wv covers 8 units; its 32 gate
// cols are ordered n = g_half*8 + unit, so lane pair (l15, l15^8) holds
// {i,g}/{f,o} of one unit -> 2x shfl_xor(8) epilogue, no LDS exchange.
// One barrier/step; seq stores + x prefetch AFTER the flag store (drain in
// the next step's wait shadow, off the flag critical path).
__global__ __launch_bounds__(256, 1) void lstm_kernel(
    const float* __restrict__ x,      // [64][464][256]
    const float* __restrict__ h0,     // [64][256]
    const float* __restrict__ c0,     // [64][256]
    const float* __restrict__ W,      // [256][1024]
    const float* __restrict__ U,      // [256][1024]
    const float* __restrict__ bias,   // [1024]
    unsigned int* __restrict__ h_bufs,   // [2][64][128] u32 (= [2][64][256] bf16)
    unsigned short* __restrict__ seq,    // [64][464][256] bf16
    float* __restrict__ out,             // [0:16384) core, [16384) hT, [32768) cT
    int* __restrict__ flags)             // flags[bgi*16 + ugi], ugi 0..7
{
  const int tid = threadIdx.x;
  const int wg  = blockIdx.x;       // 0..15
  const int bgi = wg >> 3;          // 0..1  batch group (32 rows)
  const int ugi = wg & 7;           // 0..7  unit group (32 hidden units)
  const int wv  = tid >> 6;         // wave 0..3 -> 8-unit slice
  const int ln  = tid & 63;
  const int l15 = ln & 15;
  const int q   = ln >> 4;
  const int hi  = l15 >> 3;         // 0: gates {i,g}, 1: gates {f,o}
  const int j   = l15 & 7;          // unit within wave slice

  // LDS: weight-staging buffer (prologue only) aliased with x double-buffer.
  __shared__ __align__(16) char smem[33792];   // max(32*520*2, 2*32*264*2)
  unsigned short (*Bst)[520]     = (unsigned short(*)[520])smem;      // [32][520]
  unsigned short (*xl)[32][264]  = (unsigned short(*)[32][264])smem;  // [2][32][264]

  // ---------------- Prologue: weights -> registers ----------------
  // Wave wv's 32 gate cols: n = n2*16 + hi*8 + j -> gate g = n2*2 + hi,
  // global col gc = g*256 + ubase + wv*8 + j.
  bf16x8 wW[2][8], wU[2][8];
  const int ubase = ugi * 32;
#pragma unroll
  for (int ch = 0; ch < 4; ++ch) {             // one chunk per wave's slice
    __syncthreads();                           // prev chunk's reads done
    for (int it = 0; it < 64; ++it) {          // 32 cols x 512 k = 16384 elems
      int idx = it * 256 + tid;
      int k = idx >> 5, n = idx & 31;
      int gc = (n >> 3) * 256 + ubase + ch * 8 + (n & 7);   // n>>3 = g (0..3)
      float val = (k < 256) ? W[(size_t)k * 1024 + gc]
                            : U[(size_t)(k - 256) * 1024 + gc];
      Bst[n][k] = f2bf(val);
    }
    __syncthreads();
    if (wv == ch) {
#pragma unroll
      for (int n2 = 0; n2 < 2; ++n2)
#pragma unroll
        for (int kk = 0; kk < 8; ++kk) {
          wW[n2][kk] = *(const bf16x8*)&Bst[n2 * 16 + l15][kk * 32 + q * 8];
          wU[n2][kk] = *(const bf16x8*)&Bst[n2 * 16 + l15][256 + kk * 32 + q * 8];
        }
    }
  }
  __syncthreads();   // Bst dead; xl may now be written (aliased)

  // ---------------- State: 8 (row, unit) pairs per lane (dup across hi) ----
  const int uu = ubase + wv * 8 + j;           // hidden unit
  const int rb = bgi * 32;                     // group row base
  // bias folded into acc init: bz[n2] = bias for gate n2*2+hi, unit uu
  float bz[2];
  bz[0] = bias[hi * 256 + uu];                 // i (hi=0) / f (hi=1)
  bz[1] = bias[(2 + hi) * 256 + uu];           // g (hi=0) / o (hi=1)
  float cst[2][4], hst[2][4];
#pragma unroll
  for (int mt = 0; mt < 2; ++mt)
#pragma unroll
    for (int r = 0; r < 4; ++r) {
      int row = rb + mt * 16 + q * 4 + r;
      cst[mt][r] = c0[row * HH + uu];
      hst[mt][r] = h0[row * HH + uu];
    }

  // publish h0 into buf 0 (packed u32; lanes with hi==0 && even j)
#pragma unroll
  for (int mt = 0; mt < 2; ++mt)
#pragma unroll
    for (int r = 0; r < 4; ++r) {
      unsigned short hb16 = f2bf(hst[mt][r]);
      unsigned other = (unsigned)(unsigned short)__shfl_xor((int)hb16, 1);
      if ((l15 & 9) == 0) {
        unsigned hpk = (unsigned)hb16 | (other << 16);
        int row = rb + mt * 16 + q * 4 + r;
        __hip_atomic_store(&h_bufs[row * 128 + (uu >> 1)], hpk,
                           __ATOMIC_RELAXED, __HIP_MEMORY_SCOPE_AGENT);
      }
    }

  // ---------------- x staging: thread -> (row r_own, 32 cols) ----------------
  const int r_own = tid >> 3;                  // 0..31 (row within group)
  const int xc0   = (tid & 7) * 32;
  const float* xbase = x + (size_t)(rb + r_own) * TT * HH + xc0;
  float4 xr[8];

  auto stage_x = [&](int buf) {                // xr (fp32) -> bf16 -> xl[buf]
    unsigned px[16];
#pragma unroll
    for (int i = 0; i < 8; ++i) {
      px[2*i]   = (unsigned)f2bf(xr[i].x) | ((unsigned)f2bf(xr[i].y) << 16);
      px[2*i+1] = (unsigned)f2bf(xr[i].z) | ((unsigned)f2bf(xr[i].w) << 16);
    }
#pragma unroll
    for (int s = 0; s < 4; ++s) {
      uint4 v = make_uint4(px[4*s], px[4*s+1], px[4*s+2], px[4*s+3]);
      *(uint4*)&xl[buf][r_own][xc0 + s * 8] = v;
    }
  };

#pragma unroll
  for (int i = 0; i < 8; ++i) xr[i] = ((const float4*)xbase)[i];          // t=0
  stage_x(0);
#pragma unroll
  for (int i = 0; i < 8; ++i) xr[i] = ((const float4*)(xbase + HH))[i];   // t=1

  __builtin_amdgcn_s_waitcnt(0);
  __syncthreads();
  if (tid == 0)
    __hip_atomic_store(&flags[bgi * 16 + ugi], 1, __ATOMIC_RELAXED, __HIP_MEMORY_SCOPE_AGENT);

  // ---------------- 464 recurrent steps ----------------
  for (int t = 0; t < TT; ++t) {
    const int pr  = t & 1;
    const int pwb = pr ^ 1;

    // x @ W (no h dependency; hides under flag propagation). Bias in C init.
    f32x4 acc[2][2];
#pragma unroll
    for (int mt = 0; mt < 2; ++mt)
#pragma unroll
      for (int n2 = 0; n2 < 2; ++n2)
        acc[mt][n2] = (f32x4){bz[n2], bz[n2], bz[n2], bz[n2]};
#pragma unroll
    for (int mt = 0; mt < 2; ++mt)
#pragma unroll
      for (int kk = 0; kk < 8; ++kk) {
        bf16x8 af = *(const bf16x8*)&xl[pr][mt * 16 + l15][kk * 32 + q * 8];
#pragma unroll
        for (int n2 = 0; n2 < 2; ++n2)
          acc[mt][n2] = __builtin_amdgcn_mfma_f32_16x16x32_bf16(af, wW[n2][kk], acc[mt][n2], 0, 0, 0);
      }

    wait_flags(flags, bgi * 16, t + 1);        // group's 8 WGs published h_t

    // h A-fragments (u64 relaxed agent atomic loads, coherent)
    bf16x8 hf[2][8];
#pragma unroll
    for (int mt = 0; mt < 2; ++mt) {
      const unsigned long long* hb = (const unsigned long long*)h_bufs
          + (size_t)pr * (BB * 64) + (rb + mt * 16 + l15) * 64 + q * 2;
#pragma unroll
      for (int kk = 0; kk < 8; ++kk) {
        union { unsigned long long uu64[2]; bf16x8 v; } tmp;
        tmp.uu64[0] = __hip_atomic_load(hb + kk * 8,     __ATOMIC_RELAXED, __HIP_MEMORY_SCOPE_AGENT);
        tmp.uu64[1] = __hip_atomic_load(hb + kk * 8 + 1, __ATOMIC_RELAXED, __HIP_MEMORY_SCOPE_AGENT);
        hf[mt][kk] = tmp.v;
      }
    }
#pragma unroll
    for (int mt = 0; mt < 2; ++mt)
#pragma unroll
      for (int kk = 0; kk < 8; ++kk)
#pragma unroll
        for (int n2 = 0; n2 < 2; ++n2)
          acc[mt][n2] = __builtin_amdgcn_mfma_f32_16x16x32_bf16(hf[mt][kk], wU[n2][kk], acc[mt][n2], 0, 0, 0);

    // Epilogue: lane has za=acc[.][0][r] (i or f), zb=acc[.][1][r] (g or o).
    // Pair exchange via shfl_xor(8): low sends p=i*relu(g), high sends fa;
    // second xor carries oa. Both lanes keep identical (c,h) duplicates.
    unsigned pk[2][4];                         // packed h (valid on publish lanes)
#pragma unroll
    for (int mt = 0; mt < 2; ++mt)
#pragma unroll
      for (int r = 0; r < 4; ++r) {
        float za = acc[mt][0][r];
        float zb = acc[mt][1][r];
        float sa = __builtin_amdgcn_rcpf(1.f + __expf(-za));   // sigmoid(i|f)
        float sb = __builtin_amdgcn_rcpf(1.f + __expf(-zb));   // sigmoid(o) [hi]
        float rg = fmaxf(zb, 0.f);                             // relu(g)    [lo]
        float v0 = hi ? sa : sa * rg;          // hi: fa, lo: p = i*relu(g)
        float w0 = __shfl_xor(v0, 8);
        float pe = hi ? w0 : v0;
        float fe = hi ? v0 : w0;
        float c  = fe * cst[mt][r] + pe;
        cst[mt][r] = c;
        float w1 = __shfl_xor(sb, 8);
        float oe = hi ? sb : w1;
        float h  = oe * fmaxf(c, 0.f);
        hst[mt][r] = h;
        unsigned short hb16 = f2bf(h);
        unsigned other = (unsigned)(unsigned short)__shfl_xor((int)hb16, 1);
        pk[mt][r] = (unsigned)hb16 | (other << 16);
      }

    stage_x(pwb);                              // x_{t+1} -> LDS (before barrier)

    // publish h_{t+1} (lanes hi==0, even j)
#pragma unroll
    for (int mt = 0; mt < 2; ++mt)
#pragma unroll
      for (int r = 0; r < 4; ++r)
        if ((l15 & 9) == 0) {
          int row = rb + mt * 16 + q * 4 + r;
          __hip_atomic_store(&h_bufs[pwb * (BB * 128) + row * 128 + (uu >> 1)], pk[mt][r],
                             __ATOMIC_RELAXED, __HIP_MEMORY_SCOPE_AGENT);
        }

    __builtin_amdgcn_s_waitcnt(0);             // publishes + xl writes drained
    __syncthreads();                           // whole WG drained
    if (tid == 0)
      __hip_atomic_store(&flags[bgi * 16 + ugi], t + 2,
                         __ATOMIC_RELAXED, __HIP_MEMORY_SCOPE_AGENT);

    // ---- post-flag shadow: seq stores + x prefetch (drain during next wait)
#pragma unroll
    for (int mt = 0; mt < 2; ++mt)
#pragma unroll
      for (int r = 0; r < 4; ++r)
        if ((l15 & 9) == 0) {
          int row = rb + mt * 16 + q * 4 + r;
          *(unsigned*)&seq[((size_t)row * TT + t) * HH + uu] = pk[mt][r];
        }
    {
      const int tn = (t + 2 < TT) ? (t + 2) : (TT - 1);
      const float4* p = (const float4*)(xbase + (size_t)tn * HH);
#pragma unroll
      for (int i = 0; i < 8; ++i) xr[i] = p[i];
    }
  }

  if (hi == 0)
#pragma unroll
    for (int mt = 0; mt < 2; ++mt)
#pragma unroll
      for (int r = 0; r < 4; ++r) {
        int row = rb + mt * 16 + q * 4 + r;
        out[16384 + row * HH + uu] = hst[mt][r];  // hT fp32 (un-rounded state)
        out[32768 + row * HH + uu] = cst[mt][r];  // cT
      }
}

// Dense partials: wg kb handles t = kb and kb+232; K=512 per wg.
#define DP_PA 264   // a_lds pitch (shorts)
#define DP_PW 258   // Wf pitch (floats): 258%32=2 -> 2-way on frag reads (free)
__global__ __launch_bounds__(256) void dense_partial(
    const unsigned short* __restrict__ seq,  // [64][464][256] bf16
    const float* __restrict__ Wd,            // [118784][256]
    float* __restrict__ part)                // [232][64][256]
{
  __shared__ __align__(16) char smem[64 * DP_PA * 2];   // 33792 B >= 32*DP_PW*4
  unsigned short* a_lds = (unsigned short*)smem;
  float*          Wf    = (float*)smem;

  const int kb  = blockIdx.x;     // 0..231
  const int tid = threadIdx.x;
  const int wv  = tid >> 6;       // M-tile
  const int ln  = tid & 63;
  const int l15 = ln & 15;
  const int q   = ln >> 4;

  f32x4 acc[16];
#pragma unroll
  for (int i = 0; i < 16; ++i) acc[i] = (f32x4){0.f, 0.f, 0.f, 0.f};

  for (int half = 0; half < 2; ++half) {
    const int t = kb + half * 232;
    __syncthreads();                       // prev chunk's Wf reads done (smem reuse)
#pragma unroll
    for (int it = 0; it < 8; ++it) {       // stage A: seq[0..63][t][:]
      int cidx = it * 256 + tid;
      int row  = cidx >> 5;
      int off  = (cidx & 31) * 8;
      *(bf16x8*)&a_lds[row * DP_PA + off] =
          *(const bf16x8*)(seq + ((size_t)row * TT + t) * HH + off);
    }
    __syncthreads();
    bf16x8 af[8];
#pragma unroll
    for (int kk = 0; kk < 8; ++kk)
      af[kk] = *(const bf16x8*)&a_lds[(wv * 16 + l15) * DP_PA + kk * 32 + q * 8];

    for (int ck = 0; ck < 8; ++ck) {       // K chunks of 32
      __syncthreads();                     // af in regs / prev Wf reads done
#pragma unroll
      for (int it = 0; it < 8; ++it) {     // stage Wf[32][256] fp32, coalesced
        int idx = it * 256 + tid;
        int r   = idx >> 6;
        int c4  = (idx & 63) * 4;
        float4 v = *(const float4*)(Wd + ((size_t)(t * 256 + ck * 32 + r)) * HH + c4);
        *(float2*)&Wf[r * DP_PW + c4]     = make_float2(v.x, v.y);
        *(float2*)&Wf[r * DP_PW + c4 + 2] = make_float2(v.z, v.w);
      }
      __syncthreads();
#pragma unroll
      for (int nt2 = 0; nt2 < 16; ++nt2) {
        const int n = nt2 * 16 + l15;
        bf16x8 bfr;
#pragma unroll
        for (int jj = 0; jj < 8; ++jj)
          bfr[jj] = (short)f2bf(Wf[(q * 8 + jj) * DP_PW + n]);
        acc[nt2] = __builtin_amdgcn_mfma_f32_16x16x32_bf16(af[ck], bfr, acc[nt2], 0, 0, 0);
      }
    }
  }

  float* pb = part + (size_t)kb * (BB * HH);
#pragma unroll
  for (int nt2 = 0; nt2 < 16; ++nt2)
#pragma unroll
    for (int reg = 0; reg < 4; ++reg)
      pb[(wv * 16 + q * 4 + reg) * HH + nt2 * 16 + l15] = acc[nt2][reg];
}

__global__ __launch_bounds__(256) void dense_reduce(
    const float* __restrict__ part,   // [232][16384]
    const float* __restrict__ bd,     // [256]
    float* __restrict__ out)          // d_out[0:16384)
{
  const int o = blockIdx.x * 256 + threadIdx.x;
  float s0 = 0.f, s1 = 0.f, s2 = 0.f, s3 = 0.f;
  for (int kb = 0; kb < 232; kb += 4) {
    s0 += part[(size_t)(kb    ) * 16384 + o];
    s1 += part[(size_t)(kb + 1) * 16384 + o];
    s2 += part[(size_t)(kb + 2) * 16384 + o];
    s3 += part[(size_t)(kb + 3) * 16384 + o];
  }
  float s = (s0 + s1) + (s2 + s3) + bd[o & 255];
  out[o] = fmaxf(s, 0.f);
}

extern "C" void kernel_launch(void* const* d_in, const int* in_sizes, int n_in,
                              void* d_out, int out_size, void* d_ws, size_t ws_size,
                              hipStream_t stream) {
  const float* x  = (const float*)d_in[0];
  const float* h0 = (const float*)d_in[1];
  const float* c0 = (const float*)d_in[2];
  const float* W  = (const float*)d_in[3];
  const float* U  = (const float*)d_in[4];
  const float* bv = (const float*)d_in[5];
  const float* Wd = (const float*)d_in[6];
  const float* bd = (const float*)d_in[7];
  float* out = (float*)d_out;

  // d_ws layout:
  //   [0,256)        flags (indices bgi*16+ugi; memset to 0 here)
  //   [256, +64KiB)  h_bufs  [2][64][128] u32
  //   next 15.2 MB   seq     [64][464][256] bf16
  //   next 15.2 MB   part    [232][64][256] fp32
  char* w = (char*)d_ws;
  int* flags = (int*)w;
  unsigned int*   h_bufs = (unsigned int*)(w + 256);
  unsigned short* seq    = (unsigned short*)(w + 256 + 2 * BB * HH * 2);
  float*          part   = (float*)(w + 256 + 2 * BB * HH * 2 + (size_t)BB * TT * HH * 2);

  hipMemsetAsync(d_ws, 0, 256, stream);   // reset flags every launch
  lstm_kernel<<<16, 256, 0, stream>>>(x, h0, c0, W, U, bv, h_bufs, seq, out, flags);
  dense_partial<<<232, 256, 0, stream>>>(seq, Wd, part);
  dense_reduce<<<64, 256, 0, stream>>>(part, bd, out);
}

// Round 4
// 1961.198 us; speedup vs baseline: 1.7598x; 1.6956x over previous
//
#include <hip/hip_runtime.h>

#define TT  464
#define HH  256
#define BB  64
#define NWG 64   // persistent LSTM workgroups: 2 batch-groups x 32 feature-groups

using bf16x8 = __attribute__((ext_vector_type(8))) short;   // 8 bf16 (4 VGPRs)
using f32x4  = __attribute__((ext_vector_type(4))) float;   // MFMA accumulator

__device__ __forceinline__ unsigned short f2bf(float x) {
  union { float f; unsigned u; } v; v.f = x;
  unsigned r = v.u + 0x7fffu + ((v.u >> 16) & 1u);   // RNE
  return (unsigned short)(r >> 16);
}

// Flag-array barrier wait: all 4 waves poll the 32 flags of this batch-group
// with one relaxed agent-scope load per lane (no RMW, no cache fences).
__device__ __forceinline__ void wait_flags(int* flags, int base, int target) {
  const int ln  = threadIdx.x & 63;
  int* p = &flags[base + (ln & 31)];
  for (;;) {
    int f = __hip_atomic_load(p, __ATOMIC_RELAXED, __HIP_MEMORY_SCOPE_AGENT);
    if (__all(f >= target)) break;
    __builtin_amdgcn_s_sleep(1);
  }
  asm volatile("" ::: "memory");   // compiler barrier: keep h loads below the poll
}

// Persistent LSTM: wg = (bgi: 32 batch rows) x (fgi: 8 hidden units -> 32 gate cols).
// z[32,32] = [x_t | h] @ [W;U]-slice via mfma_f32_16x16x32_bf16; state fp32 in regs.
// Round-4 theory under test: the per-kk __hip_atomic_load h-fragments were
// SERIALIZED (one RTT each, ~16 RTTs/step dominated the 10.4k cy/step).
// Fix: one inline-asm block of 8 global_load_dwordx4 sc0 sc1 (coherence-point
// reads, pipelined) + a single s_waitcnt -> 1 RTT. seq stores moved post-flag.
__global__ __launch_bounds__(256) void lstm_kernel(
    const float* __restrict__ x,      // [64][464][256]
    const float* __restrict__ h0,     // [64][256]
    const float* __restrict__ c0,     // [64][256]
    const float* __restrict__ W,      // [256][1024]
    const float* __restrict__ U,      // [256][1024]
    const float* __restrict__ bias,   // [1024]
    unsigned int* __restrict__ h_bufs,   // [2][64][128] u32 (= [2][64][256] bf16)
    unsigned short* __restrict__ seq,    // [64][464][256] bf16
    float* __restrict__ out,             // d_out: [0:16384) core, [16384) hT, [32768) cT
    int* __restrict__ flags)             // [64]
{
  const int tid = threadIdx.x;
  const int wg  = blockIdx.x;
  const int bgi = wg >> 5;          // 0..1
  const int fgi = wg & 31;          // 0..31
  const int wv  = tid >> 6;         // wave 0..3
  const int ln  = tid & 63;
  const int mt  = wv >> 1;          // M-tile (16 rows)
  const int nt  = wv & 1;           // N-tile (16 cols)
  const int l15 = ln & 15;
  const int q   = ln >> 4;

  __shared__ unsigned short Bt[32][520];     // [W;U] slice, n-major, K=512
  __shared__ unsigned short x_lds[32][264];  // x_t slice bf16
  __shared__ float          z_lds[32][36];   // MFMA result exchange

  // Stage combined weights: Bt[n][k]; n = g*8+j -> global col g*256 + fgi*8 + j
  for (int it = 0; it < 64; ++it) {
    int i  = it * 256 + tid;
    int k  = i >> 5;                 // 0..511
    int n  = i & 31;
    int gc = (n >> 3) * 256 + fgi * 8 + (n & 7);
    float wval = (k < 256) ? W[(size_t)k * 1024 + gc] : U[(size_t)(k - 256) * 1024 + gc];
    Bt[n][k] = f2bf(wval);
  }

  // Per-thread owned state: (r_own, j_own) one (batch-row, hidden-unit) pair
  const int r_own = tid >> 3;        // 0..31
  const int j_own = tid & 7;         // 0..7
  const int brow  = bgi * 32 + r_own;
  const int col   = fgi * 8 + j_own;
  float c = c0[brow * HH + col];
  float h = h0[brow * HH + col];
  const float b_i = bias[        col];
  const float b_f = bias[  HH  + col];
  const float b_g = bias[2*HH  + col];
  const float b_o = bias[3*HH  + col];

  // publish h0 into buf 0 (packed pairs, relaxed agent atomics -> coherent stores)
  {
    unsigned short hb16 = f2bf(h);
    unsigned other = (unsigned)(unsigned short)__shfl_xor((int)hb16, 1);
    if (!(tid & 1)) {
      unsigned hpk = (unsigned)hb16 | (other << 16);
      __hip_atomic_store(&h_bufs[brow * 128 + (col >> 1)], hpk,
                         __ATOMIC_RELAXED, __HIP_MEMORY_SCOPE_AGENT);
    }
  }

  // x prefetch mapping: thread -> (row r_own, cols j_own*32 .. +31)
  const int xc0  = j_own * 32;
  float4 xr[8];
  {
    const float4* p = (const float4*)(x + ((size_t)brow * TT + 0) * HH + xc0);
#pragma unroll
    for (int i = 0; i < 8; ++i) xr[i] = p[i];
  }

  __builtin_amdgcn_s_waitcnt(0);
  __syncthreads();
  if (tid == 0)
    __hip_atomic_store(&flags[wg], 1, __ATOMIC_RELAXED, __HIP_MEMORY_SCOPE_AGENT);

  for (int t = 0; t < TT; ++t) {
    const int pr  = t & 1;           // read buffer
    const int pwb = pr ^ 1;          // write buffer

    // x[t] (prefetched last iter) -> bf16 -> LDS
    {
      unsigned px[16];
#pragma unroll
      for (int i = 0; i < 8; ++i) {
        px[2*i]   = (unsigned)f2bf(xr[i].x) | ((unsigned)f2bf(xr[i].y) << 16);
        px[2*i+1] = (unsigned)f2bf(xr[i].z) | ((unsigned)f2bf(xr[i].w) << 16);
      }
#pragma unroll
      for (int s = 0; s < 4; ++s) {
        uint4 v = make_uint4(px[4*s], px[4*s+1], px[4*s+2], px[4*s+3]);
        *(uint4*)&x_lds[r_own][xc0 + s * 8] = v;
      }
    }
    // prefetch x[t+1]
    {
      const int tn = (t + 1 < TT) ? (t + 1) : (TT - 1);
      const float4* p = (const float4*)(x + ((size_t)brow * TT + tn) * HH + xc0);
#pragma unroll
      for (int i = 0; i < 8; ++i) xr[i] = p[i];
    }

    __syncthreads();                 // (A) x_lds ready

    // x @ W half first: no h dependency, hides in barrier wait
    f32x4 acc = {0.f, 0.f, 0.f, 0.f};
#pragma unroll
    for (int kk = 0; kk < 8; ++kk) {
      bf16x8 afr = *(const bf16x8*)&x_lds[mt * 16 + l15][kk * 32 + q * 8];
      bf16x8 bfr = *(const bf16x8*)&Bt[nt * 16 + l15][kk * 32 + q * 8];
      acc = __builtin_amdgcn_mfma_f32_16x16x32_bf16(afr, bfr, acc, 0, 0, 0);
    }

    wait_flags(flags, bgi * 32, t + 1);   // all group wgs published h_t

    // h A-fragments: 8 pipelined coherence-point loads, ONE waitcnt (1 RTT).
    // hf[kk] element e = h[row = bgi*32+mt*16+l15][col = kk*32 + q*8 + e]
    bf16x8 hf[8];
    {
      const char* hb = (const char*)h_bufs + (size_t)pr * (BB * HH * 2)
                     + (size_t)(bgi * 32 + mt * 16 + l15) * (HH * 2) + q * 16;
      asm volatile(
        "global_load_dwordx4 %0, %[ad], off sc0 sc1\n\t"
        "global_load_dwordx4 %1, %[ad], off offset:64 sc0 sc1\n\t"
        "global_load_dwordx4 %2, %[ad], off offset:128 sc0 sc1\n\t"
        "global_load_dwordx4 %3, %[ad], off offset:192 sc0 sc1\n\t"
        "global_load_dwordx4 %4, %[ad], off offset:256 sc0 sc1\n\t"
        "global_load_dwordx4 %5, %[ad], off offset:320 sc0 sc1\n\t"
        "global_load_dwordx4 %6, %[ad], off offset:384 sc0 sc1\n\t"
        "global_load_dwordx4 %7, %[ad], off offset:448 sc0 sc1\n\t"
        "s_waitcnt vmcnt(0)"
        : "=&v"(hf[0]), "=&v"(hf[1]), "=&v"(hf[2]), "=&v"(hf[3]),
          "=&v"(hf[4]), "=&v"(hf[5]), "=&v"(hf[6]), "=&v"(hf[7])
        : [ad]"v"(hb)
        : "memory");
    }
#pragma unroll
    for (int kk = 0; kk < 8; ++kk) {      // h @ U part (K 256..511)
      bf16x8 bfr = *(const bf16x8*)&Bt[nt * 16 + l15][256 + kk * 32 + q * 8];
      acc = __builtin_amdgcn_mfma_f32_16x16x32_bf16(hf[kk], bfr, acc, 0, 0, 0);
    }
    // C/D layout: col = lane&15, row = (lane>>4)*4 + reg (m89-verified)
#pragma unroll
    for (int reg = 0; reg < 4; ++reg)
      z_lds[mt * 16 + q * 4 + reg][nt * 16 + l15] = acc[reg];

    __syncthreads();                 // (C) z ready

    // gates: n = g*8 + j  (i:0..7, f:8..15, g:16..23, o:24..31)
    float zi = z_lds[r_own][      j_own] + b_i;
    float zf = z_lds[r_own][ 8 + j_own] + b_f;
    float zg = z_lds[r_own][16 + j_own] + b_g;
    float zo = z_lds[r_own][24 + j_own] + b_o;
    float gi = 1.f / (1.f + __expf(-zi));
    float gf = 1.f / (1.f + __expf(-zf));
    float go = 1.f / (1.f + __expf(-zo));
    float gg = fmaxf(zg, 0.f);
    c = gf * c + gi * gg;
    h = go * fmaxf(c, 0.f);
    unsigned short hb16 = f2bf(h);

    // publish h_{t+1}: packed u32, relaxed agent atomic (coherent store)
    {
      unsigned other = (unsigned)(unsigned short)__shfl_xor((int)hb16, 1);
      if (!(tid & 1)) {
        unsigned hpk = (unsigned)hb16 | (other << 16);
        __hip_atomic_store(&h_bufs[pwb * (BB * 128) + brow * 128 + (col >> 1)], hpk,
                           __ATOMIC_RELAXED, __HIP_MEMORY_SCOPE_AGENT);
      }
    }
    __builtin_amdgcn_s_waitcnt(0);   // own publishes at coherent point
    __syncthreads();                 // (D) whole wg's publishes drained
    if (tid == 0)
      __hip_atomic_store(&flags[wg], t + 2, __ATOMIC_RELAXED, __HIP_MEMORY_SCOPE_AGENT);

    // post-flag shadow: seq store (kernel-boundary coherence; drains during
    // next step's wait, off the flag critical path)
    seq[((size_t)brow * TT + t) * HH + col] = hb16;
  }

  out[16384 + brow * HH + col] = h;   // hT fp32 (un-rounded state)
  out[32768 + brow * HH + col] = c;   // cT
}

// Dense partials: wg kb handles t = kb and kb+232; K=512 per wg.
// Wd staged via coalesced float4 loads into LDS (aliased with A-tile), read-time bf16.
#define DP_PA 264   // a_lds pitch (shorts)
#define DP_PW 258   // Wf pitch (floats): 258%32=2 -> 2-way on frag reads (free)
__global__ __launch_bounds__(256) void dense_partial(
    const unsigned short* __restrict__ seq,  // [64][464][256] bf16
    const float* __restrict__ Wd,            // [118784][256]
    float* __restrict__ part)                // [232][64][256]
{
  __shared__ __align__(16) char smem[64 * DP_PA * 2];   // 33792 B >= 32*DP_PW*4
  unsigned short* a_lds = (unsigned short*)smem;
  float*          Wf    = (float*)smem;

  const int kb  = blockIdx.x;     // 0..231
  const int tid = threadIdx.x;
  const int wv  = tid >> 6;       // M-tile
  const int ln  = tid & 63;
  const int l15 = ln & 15;
  const int q   = ln >> 4;

  f32x4 acc[16];
#pragma unroll
  for (int i = 0; i < 16; ++i) acc[i] = (f32x4){0.f, 0.f, 0.f, 0.f};

  for (int half = 0; half < 2; ++half) {
    const int t = kb + half * 232;
    __syncthreads();                       // prev chunk's Wf reads done (smem reuse)
#pragma unroll
    for (int it = 0; it < 8; ++it) {       // stage A: seq[0..63][t][:]
      int cidx = it * 256 + tid;
      int row  = cidx >> 5;
      int off  = (cidx & 31) * 8;
      *(bf16x8*)&a_lds[row * DP_PA + off] =
          *(const bf16x8*)(seq + ((size_t)row * TT + t) * HH + off);
    }
    __syncthreads();
    bf16x8 af[8];
#pragma unroll
    for (int kk = 0; kk < 8; ++kk)
      af[kk] = *(const bf16x8*)&a_lds[(wv * 16 + l15) * DP_PA + kk * 32 + q * 8];

    for (int ck = 0; ck < 8; ++ck) {       // K chunks of 32
      __syncthreads();                     // af in regs / prev Wf reads done
#pragma unroll
      for (int it = 0; it < 8; ++it) {     // stage Wf[32][256] fp32, coalesced
        int idx = it * 256 + tid;
        int r   = idx >> 6;
        int c4  = (idx & 63) * 4;
        float4 v = *(const float4*)(Wd + ((size_t)(t * 256 + ck * 32 + r)) * HH + c4);
        *(float2*)&Wf[r * DP_PW + c4]     = make_float2(v.x, v.y);
        *(float2*)&Wf[r * DP_PW + c4 + 2] = make_float2(v.z, v.w);
      }
      __syncthreads();
#pragma unroll
      for (int nt2 = 0; nt2 < 16; ++nt2) {
        const int n = nt2 * 16 + l15;
        bf16x8 bfr;
#pragma unroll
        for (int j = 0; j < 8; ++j)
          bfr[j] = (short)f2bf(Wf[(q * 8 + j) * DP_PW + n]);
        acc[nt2] = __builtin_amdgcn_mfma_f32_16x16x32_bf16(af[ck], bfr, acc[nt2], 0, 0, 0);
      }
    }
  }

  float* pb = part + (size_t)kb * (BB * HH);
#pragma unroll
  for (int nt2 = 0; nt2 < 16; ++nt2)
#pragma unroll
    for (int reg = 0; reg < 4; ++reg)
      pb[(wv * 16 + q * 4 + reg) * HH + nt2 * 16 + l15] = acc[nt2][reg];
}

__global__ __launch_bounds__(256) void dense_reduce(
    const float* __restrict__ part,   // [232][16384]
    const float* __restrict__ bd,     // [256]
    float* __restrict__ out)          // d_out[0:16384)
{
  const int o = blockIdx.x * 256 + threadIdx.x;
  float s0 = 0.f, s1 = 0.f, s2 = 0.f, s3 = 0.f;
  for (int kb = 0; kb < 232; kb += 4) {
    s0 += part[(size_t)(kb    ) * 16384 + o];
    s1 += part[(size_t)(kb + 1) * 16384 + o];
    s2 += part[(size_t)(kb + 2) * 16384 + o];
    s3 += part[(size_t)(kb + 3) * 16384 + o];
  }
  float s = (s0 + s1) + (s2 + s3) + bd[o & 255];
  out[o] = fmaxf(s, 0.f);
}

extern "C" void kernel_launch(void* const* d_in, const int* in_sizes, int n_in,
                              void* d_out, int out_size, void* d_ws, size_t ws_size,
                              hipStream_t stream) {
  const float* x  = (const float*)d_in[0];
  const float* h0 = (const float*)d_in[1];
  const float* c0 = (const float*)d_in[2];
  const float* W  = (const float*)d_in[3];
  const float* U  = (const float*)d_in[4];
  const float* bv = (const float*)d_in[5];
  const float* Wd = (const float*)d_in[6];
  const float* bd = (const float*)d_in[7];
  float* out = (float*)d_out;

  // d_ws layout:
  //   [0,256)        flags[64]       (memset to 0 here)
  //   [256, +64KiB)  h_bufs  [2][64][256] bf16
  //   next 15.2 MB   seq     [64][464][256] bf16
  //   next 15.2 MB   part    [232][64][256] fp32     (total ~30.5 MB)
  char* w = (char*)d_ws;
  int* flags = (int*)w;
  unsigned int*   h_bufs = (unsigned int*)(w + 256);
  unsigned short* seq    = (unsigned short*)(w + 256 + 2 * BB * HH * 2);
  float*          part   = (float*)(w + 256 + 2 * BB * HH * 2 + (size_t)BB * TT * HH * 2);

  hipMemsetAsync(d_ws, 0, 256, stream);   // reset flags every launch
  lstm_kernel<<<NWG, 256, 0, stream>>>(x, h0, c0, W, U, bv, h_bufs, seq, out, flags);
  dense_partial<<<232, 256, 0, stream>>>(seq, Wd, part);
  dense_reduce<<<64, 256, 0, stream>>>(part, bd, out);
}